// Round 3
// baseline (1412.351 us; speedup 1.0000x reference)
//
#include <hip/hip_runtime.h>
#include <math.h>

#define N_NODES 50000
#define DIM     128
#define NHEAD   8
#define HDIM    16
#define NLAYER  2
#define NTYPE   4
#define NREL    8
#define NEDGE   800000
#define RB      256
#define GN      8      // nodes per block in grouped qkv/out kernels
#define NK      (N_NODES * NREL)   // (dst,etype) buckets

// ================= init: rank within type =================

__global__ void k_hist(const int* __restrict__ ntype, int* __restrict__ hist, int n) {
    __shared__ int cnt[NTYPE];
    if (threadIdx.x < NTYPE) cnt[threadIdx.x] = 0;
    __syncthreads();
    int i = blockIdx.x * RB + threadIdx.x;
    if (i < n) atomicAdd(&cnt[ntype[i]], 1);
    __syncthreads();
    if (threadIdx.x < NTYPE) hist[blockIdx.x * NTYPE + threadIdx.x] = cnt[threadIdx.x];
}

__global__ void k_prefix(const int* __restrict__ hist, int* __restrict__ off, int nb) {
    int t = threadIdx.x;
    if (t >= NTYPE) return;
    int acc = 0;
    for (int b = 0; b < nb; b++) { off[b * NTYPE + t] = acc; acc += hist[b * NTYPE + t]; }
}

__global__ void k_rank(const int* __restrict__ ntype, const int* __restrict__ off,
                       int* __restrict__ rank, int n) {
    __shared__ int ty[RB];
    int i = blockIdx.x * RB + threadIdx.x;
    int t = (i < n) ? ntype[i] : -1;
    ty[threadIdx.x] = t;
    __syncthreads();
    if (i < n) {
        int c = 0;
        for (int j = 0; j < (int)threadIdx.x; j++) c += (ty[j] == t);
        rank[i] = off[blockIdx.x * NTYPE + t] + c;
    }
}

__global__ void k_embed(const float* __restrict__ embed, const int* __restrict__ ntype,
                        const int* __restrict__ rank, float* __restrict__ h) {
    int i = blockIdx.x;
    int t = ntype[i], r = rank[i];
    h[(size_t)i * DIM + threadIdx.x] = embed[((size_t)t * N_NODES + r) * DIM + threadIdx.x];
}

__global__ void k_typeoff(const int* __restrict__ hist, const int* __restrict__ boff,
                          int nb, int* __restrict__ typeoff) {
    if (threadIdx.x == 0 && blockIdx.x == 0) {
        int acc = 0;
        for (int t = 0; t < NTYPE; t++) {
            typeoff[t] = acc;
            acc += boff[(nb - 1) * NTYPE + t] + hist[(nb - 1) * NTYPE + t];
        }
    }
}

__global__ void k_perm(const int* __restrict__ ntype, const int* __restrict__ rank,
                       const int* __restrict__ typeoff, int* __restrict__ perm, int n) {
    int i = blockIdx.x * 256 + threadIdx.x;
    if (i < n) perm[typeoff[ntype[i]] + rank[i]] = i;
}

// ================= (dst,etype)-sorted CSR build =================

__global__ void k_deg2(const int* __restrict__ dst, const int* __restrict__ etype,
                       int* __restrict__ deg) {
    int e = blockIdx.x * 256 + threadIdx.x;
    if (e < NEDGE) atomicAdd(&deg[dst[e] * NREL + etype[e]], 1);
}

__global__ void k_scan1(const int* __restrict__ deg, int* __restrict__ rs,
                        int* __restrict__ bsum, int n) {
    __shared__ int sh[256];
    int i = blockIdx.x * 256 + threadIdx.x;
    int v = (i < n) ? deg[i] : 0;
    sh[threadIdx.x] = v;
    __syncthreads();
    for (int off = 1; off < 256; off <<= 1) {
        int x = (threadIdx.x >= off) ? sh[threadIdx.x - off] : 0;
        __syncthreads();
        sh[threadIdx.x] += x;
        __syncthreads();
    }
    if (i < n) rs[i] = sh[threadIdx.x] - v;
    if (threadIdx.x == 255) bsum[blockIdx.x] = sh[255];
}

__global__ void k_scan2b(int* __restrict__ bsum, int nb) {
    __shared__ int sh[256];
    __shared__ int carry;
    if (threadIdx.x == 0) carry = 0;
    __syncthreads();
    for (int base = 0; base < nb; base += 256) {
        int i = base + threadIdx.x;
        int v = (i < nb) ? bsum[i] : 0;
        sh[threadIdx.x] = v;
        __syncthreads();
        for (int off = 1; off < 256; off <<= 1) {
            int x = (threadIdx.x >= off) ? sh[threadIdx.x - off] : 0;
            __syncthreads();
            sh[threadIdx.x] += x;
            __syncthreads();
        }
        if (i < nb) bsum[i] = sh[threadIdx.x] - v + carry;
        __syncthreads();
        if (threadIdx.x == 0) carry += sh[255];
        __syncthreads();
    }
}

__global__ void k_scan3(int* __restrict__ rs, const int* __restrict__ bsum, int n) {
    int i = blockIdx.x * 256 + threadIdx.x;
    if (i < n) rs[i] += bsum[blockIdx.x];
    if (i == 0) rs[n] = NEDGE;
}

__global__ void k_scatter2(const int* __restrict__ src, const int* __restrict__ dst,
                           const int* __restrict__ etype, const int* __restrict__ rs,
                           int* __restrict__ cur, int* __restrict__ esrc) {
    int e = blockIdx.x * 256 + threadIdx.x;
    if (e < NEDGE) {
        int key = dst[e] * NREL + etype[e];
        int p = atomicAdd(&cur[key], 1);
        esrc[rs[key] + p] = src[e];
    }
}

// ================= typed k/q/v projection, 8 same-type nodes/block =================

__global__ __launch_bounds__(128) void k_qkv_g(
        const float* __restrict__ h, const int* __restrict__ perm, const int* __restrict__ ntype,
        const float* __restrict__ Wk, const float* __restrict__ Wq, const float* __restrict__ Wv,
        float* __restrict__ kout, float* __restrict__ qout, float* __restrict__ vout, int n) {
    int o = threadIdx.x;
    int base = blockIdx.x * GN;
    __shared__ float xs[GN][DIM];
    __shared__ int nodes[GN];
    __shared__ int types[GN];
    if (o < GN) {
        int idx = base + o;
        int nd = (idx < n) ? perm[idx] : -1;
        nodes[o] = nd;
        types[o] = (nd >= 0) ? ntype[nd] : -1;
    }
    __syncthreads();
    #pragma unroll
    for (int nn = 0; nn < GN; nn++)
        if (nodes[nn] >= 0) xs[nn][o] = h[(size_t)nodes[nn] * DIM + o];
    __syncthreads();
    bool same = (nodes[GN - 1] >= 0) && (types[0] == types[GN - 1]);
    if (same) {
        int t = types[0];
        const float* wk = Wk + (size_t)t * DIM * DIM;
        const float* wq = Wq + (size_t)t * DIM * DIM;
        const float* wv = Wv + (size_t)t * DIM * DIM;
        float ak[GN], aq[GN], av[GN];
        #pragma unroll
        for (int nn = 0; nn < GN; nn++) { ak[nn] = 0.f; aq[nn] = 0.f; av[nn] = 0.f; }
        for (int d = 0; d < DIM; d++) {
            float wkv = wk[d * DIM + o], wqv = wq[d * DIM + o], wvv = wv[d * DIM + o];
            #pragma unroll
            for (int nn = 0; nn < GN; nn++) {
                float xv = xs[nn][d];
                ak[nn] = fmaf(xv, wkv, ak[nn]);
                aq[nn] = fmaf(xv, wqv, aq[nn]);
                av[nn] = fmaf(xv, wvv, av[nn]);
            }
        }
        #pragma unroll
        for (int nn = 0; nn < GN; nn++) {
            size_t p = (size_t)nodes[nn] * DIM + o;
            kout[p] = ak[nn]; qout[p] = aq[nn]; vout[p] = av[nn];
        }
    } else {
        #pragma unroll
        for (int nn = 0; nn < GN; nn++) {
            if (nodes[nn] < 0) continue;
            int t = types[nn];
            const float* wk = Wk + (size_t)t * DIM * DIM;
            const float* wq = Wq + (size_t)t * DIM * DIM;
            const float* wv = Wv + (size_t)t * DIM * DIM;
            float ak = 0.f, aq = 0.f, av = 0.f;
            for (int d = 0; d < DIM; d++) {
                float xv = xs[nn][d];
                ak = fmaf(xv, wk[d * DIM + o], ak);
                aq = fmaf(xv, wq[d * DIM + o], aq);
                av = fmaf(xv, wv[d * DIM + o], av);
            }
            size_t p = (size_t)nodes[nn] * DIM + o;
            kout[p] = ak; qout[p] = aq; vout[p] = av;
        }
    }
}

// ================= fused per-dst-node attention (register accumulators) =================
// Block = 128 threads = one dst node. thread (hh = tid>>4, oo = tid&15).
// CSR sorted by (dst, et): per et-segment, et is uniform -> register acc, shfl flush.
// No __syncthreads and no LDS writes inside the edge loop.

__global__ __launch_bounds__(128) void k_fused2(
        const float* __restrict__ kbuf, const float* __restrict__ qbuf, const float* __restrict__ vbuf,
        const int* __restrict__ rs2, const int* __restrict__ esrc,
        const float* __restrict__ ratt, const float* __restrict__ rmsg, const float* __restrict__ rpri,
        float* __restrict__ agg) {
    int node = blockIdx.x;
    int tid = threadIdx.x;
    int hh = tid >> 4, oo = tid & 15;
    int lane = tid & 63;
    int gbase = lane & 0x30;           // 16-lane group base within wave

    __shared__ float q_s[DIM];
    __shared__ float u_s[NREL][NHEAD][HDIM];   // (W_att q) * pri * 0.25 per etype

    q_s[tid] = qbuf[(size_t)node * DIM + tid];
    __syncthreads();

    // prologue: u_s[et][hh][d] ; thread d = oo
    const float* qh = &q_s[hh * HDIM];
    #pragma unroll
    for (int et = 0; et < NREL; et++) {
        const float4* w4 = (const float4*)(ratt + ((size_t)(hh * NREL + et) * HDIM + oo) * HDIM);
        float4 w0 = w4[0], w1 = w4[1], w2 = w4[2], w3 = w4[3];
        float s = w0.x * qh[0] + w0.y * qh[1] + w0.z * qh[2] + w0.w * qh[3]
                + w1.x * qh[4] + w1.y * qh[5] + w1.z * qh[6] + w1.w * qh[7]
                + w2.x * qh[8] + w2.y * qh[9] + w2.z * qh[10] + w2.w * qh[11]
                + w3.x * qh[12] + w3.y * qh[13] + w3.z * qh[14] + w3.w * qh[15];
        u_s[et][hh][oo] = s * rpri[hh * NREL + et] * 0.25f;
    }
    __syncthreads();

    float m_h = -1e30f, s_h = 0.f, out = 0.f;

    #pragma unroll 1
    for (int et = 0; et < NREL; et++) {
        int e0 = rs2[node * NREL + et];
        int e1 = rs2[node * NREL + et + 1];
        if (e0 == e1) continue;
        float acc = 0.f;
        const float* u = &u_s[et][hh][0];

        for (int base = e0; base < e1; base += HDIM) {
            int cnt = min(HDIM, e1 - base);
            // lane owns edge c = oo for head hh
            int sidx = esrc[base + min(oo, cnt - 1)];
            const float4* kr = (const float4*)(kbuf + (size_t)sidx * DIM + hh * HDIM);
            float4 k0 = kr[0], k1 = kr[1], k2 = kr[2], k3 = kr[3];
            float a = k0.x * u[0] + k0.y * u[1] + k0.z * u[2] + k0.w * u[3]
                    + k1.x * u[4] + k1.y * u[5] + k1.z * u[6] + k1.w * u[7]
                    + k2.x * u[8] + k2.y * u[9] + k2.z * u[10] + k2.w * u[11]
                    + k3.x * u[12] + k3.y * u[13] + k3.z * u[14] + k3.w * u[15];
            if (oo >= cnt) a = -1e30f;
            // 16-lane group online softmax
            float cmax = a;
            cmax = fmaxf(cmax, __shfl_xor(cmax, 1));
            cmax = fmaxf(cmax, __shfl_xor(cmax, 2));
            cmax = fmaxf(cmax, __shfl_xor(cmax, 4));
            cmax = fmaxf(cmax, __shfl_xor(cmax, 8));
            float m_new = fmaxf(m_h, cmax);
            float r = __expf(m_h - m_new);
            float p = __expf(a - m_new);
            float psum = p;
            psum += __shfl_xor(psum, 1);
            psum += __shfl_xor(psum, 2);
            psum += __shfl_xor(psum, 4);
            psum += __shfl_xor(psum, 8);
            s_h = s_h * r + psum;
            m_h = m_new;
            out *= r;
            acc *= r;
            // p-weighted v accumulate: lane is v-dim oo; loads independent, pipelined
            float accadd = 0.f;
            for (int cc = 0; cc < cnt; cc++) {
                float pc = __shfl(p, gbase | cc);
                int sc = __shfl(sidx, gbase | cc);
                accadd = fmaf(pc, vbuf[(size_t)sc * DIM + tid], accadd);
            }
            acc += accadd;
        }
        // flush segment through W_msg[et]: out[hh][oo] += sum_d acc[hh][d] * w[d][oo]
        const float* w = rmsg + (size_t)(hh * NREL + et) * HDIM * HDIM;
        #pragma unroll
        for (int d = 0; d < HDIM; d++) {
            float ad = __shfl(acc, gbase | d);
            out = fmaf(ad, w[d * HDIM + oo], out);
        }
    }

    agg[(size_t)node * DIM + tid] = out / (s_h + 1e-9f);
}

// ================= output projection + skip + LayerNorm + residual, grouped =================

__global__ __launch_bounds__(128) void k_out_g(
        const float* __restrict__ agg, float* __restrict__ h,
        const int* __restrict__ perm, const int* __restrict__ ntype,
        const float* __restrict__ Wa, const float* __restrict__ skip,
        const float* __restrict__ ln_g, const float* __restrict__ ln_b, int n) {
    int o = threadIdx.x;
    int base = blockIdx.x * GN;
    __shared__ float xs[GN][DIM];
    __shared__ float hcs[GN][DIM + 1];
    __shared__ int nodes[GN];
    __shared__ int types[GN];
    __shared__ float mu_s[GN], rs_s[GN];
    if (o < GN) {
        int idx = base + o;
        int nd = (idx < n) ? perm[idx] : -1;
        nodes[o] = nd;
        types[o] = (nd >= 0) ? ntype[nd] : -1;
    }
    __syncthreads();
    #pragma unroll
    for (int nn = 0; nn < GN; nn++)
        if (nodes[nn] >= 0) xs[nn][o] = agg[(size_t)nodes[nn] * DIM + o];
    __syncthreads();
    bool same = (nodes[GN - 1] >= 0) && (types[0] == types[GN - 1]);
    if (same) {
        int t = types[0];
        const float* w = Wa + (size_t)t * DIM * DIM;
        float acc[GN];
        #pragma unroll
        for (int nn = 0; nn < GN; nn++) acc[nn] = 0.f;
        for (int d = 0; d < DIM; d++) {
            float wv = w[d * DIM + o];
            #pragma unroll
            for (int nn = 0; nn < GN; nn++) acc[nn] = fmaf(xs[nn][d], wv, acc[nn]);
        }
        float alpha = 1.f / (1.f + __expf(-skip[t]));
        #pragma unroll
        for (int nn = 0; nn < GN; nn++) {
            float hp = h[(size_t)nodes[nn] * DIM + o];
            hcs[nn][o] = acc[nn] * alpha + hp * (1.f - alpha);
        }
    } else {
        #pragma unroll
        for (int nn = 0; nn < GN; nn++) {
            if (nodes[nn] < 0) continue;
            int t = types[nn];
            const float* w = Wa + (size_t)t * DIM * DIM;
            float a0 = 0.f;
            for (int d = 0; d < DIM; d++) a0 = fmaf(xs[nn][d], w[d * DIM + o], a0);
            float alpha = 1.f / (1.f + __expf(-skip[t]));
            float hp = h[(size_t)nodes[nn] * DIM + o];
            hcs[nn][o] = a0 * alpha + hp * (1.f - alpha);
        }
    }
    __syncthreads();
    {
        int g = o >> 4, j = o & 15;
        if (nodes[g] >= 0) {
            float s = 0.f;
            for (int d = j; d < DIM; d += 16) s += hcs[g][d];
            #pragma unroll
            for (int m = 1; m < 16; m <<= 1) s += __shfl_xor(s, m);
            float mu = s * (1.f / DIM);
            float v = 0.f;
            for (int d = j; d < DIM; d += 16) { float dv = hcs[g][d] - mu; v = fmaf(dv, dv, v); }
            #pragma unroll
            for (int m = 1; m < 16; m <<= 1) v += __shfl_xor(v, m);
            if (j == 0) { mu_s[g] = mu; rs_s[g] = rsqrtf(v * (1.f / DIM) + 1e-5f); }
        }
    }
    __syncthreads();
    float g_o = ln_g[o], b_o = ln_b[o];
    #pragma unroll
    for (int nn = 0; nn < GN; nn++) {
        if (nodes[nn] >= 0) {
            float hp = h[(size_t)nodes[nn] * DIM + o];
            h[(size_t)nodes[nn] * DIM + o] = (hcs[nn][o] - mu_s[nn]) * rs_s[nn] * g_o + b_o + hp;
        }
    }
}

// ================= host =================

extern "C" void kernel_launch(void* const* d_in, const int* in_sizes, int n_in,
                              void* d_out, int out_size, void* d_ws, size_t ws_size,
                              hipStream_t stream) {
    const float* embed = (const float*)d_in[0];
    const float* Wk    = (const float*)d_in[1];
    const float* Wq    = (const float*)d_in[2];
    const float* Wv    = (const float*)d_in[3];
    const float* Wa    = (const float*)d_in[4];
    const float* ratt  = (const float*)d_in[5];
    const float* rmsg  = (const float*)d_in[6];
    const float* rpri  = (const float*)d_in[7];
    const float* skip  = (const float*)d_in[8];
    const float* ln_g  = (const float*)d_in[9];
    const float* ln_b  = (const float*)d_in[10];
    const int*   src   = (const int*)d_in[11];
    const int*   dst   = (const int*)d_in[12];
    const int*   ntype = (const int*)d_in[13];
    const int*   etype = (const int*)d_in[14];

    float* h = (float*)d_out;

    const size_t ND = (size_t)N_NODES * DIM;
    float* kbuf = (float*)d_ws;
    float* qbuf = kbuf + ND;
    float* vbuf = qbuf + ND;
    int* rs2  = (int*)(vbuf + ND);               // NK+1
    int* deg2 = rs2 + (NK + 1);                  // NK
    int* cur2 = deg2 + NK;                       // NK
    int* esrc = cur2 + NK;                       // E
    int* bsum = esrc + NEDGE;                    // 2048
    int* rank = bsum + 2048;                     // N
    const int nb = (N_NODES + RB - 1) / RB;
    int* hist = rank + N_NODES;                  // nb*NTYPE
    int* boff = hist + nb * NTYPE;               // nb*NTYPE
    int* typeoff = boff + nb * NTYPE;            // NTYPE
    int* perm = typeoff + NTYPE;                 // N
    float* agg = qbuf;                           // alias: q dead once fused block read its row

    const int EB = (NEDGE + 255) / 256;
    const int nb2 = (NK + 255) / 256;            // 1563

    // ---- init: rank-within-type, embedding, type permutation ----
    k_hist<<<nb, RB, 0, stream>>>(ntype, hist, N_NODES);
    k_prefix<<<1, 64, 0, stream>>>(hist, boff, nb);
    k_rank<<<nb, RB, 0, stream>>>(ntype, boff, rank, N_NODES);
    k_embed<<<N_NODES, DIM, 0, stream>>>(embed, ntype, rank, h);
    k_typeoff<<<1, 64, 0, stream>>>(hist, boff, nb, typeoff);
    k_perm<<<nb, 256, 0, stream>>>(ntype, rank, typeoff, perm, N_NODES);

    // ---- (dst,etype)-sorted CSR build (once; graph static across layers) ----
    hipMemsetAsync(deg2, 0, (size_t)NK * sizeof(int), stream);
    hipMemsetAsync(cur2, 0, (size_t)NK * sizeof(int), stream);
    k_deg2<<<EB, 256, 0, stream>>>(dst, etype, deg2);
    k_scan1<<<nb2, 256, 0, stream>>>(deg2, rs2, bsum, NK);
    k_scan2b<<<1, 256, 0, stream>>>(bsum, nb2);
    k_scan3<<<nb2, 256, 0, stream>>>(rs2, bsum, NK);
    k_scatter2<<<EB, 256, 0, stream>>>(src, dst, etype, rs2, cur2, esrc);

    const int NGB = N_NODES / GN;

    for (int l = 0; l < NLAYER; l++) {
        const float* Wk_l = Wk + (size_t)l * NTYPE * DIM * DIM;
        const float* Wq_l = Wq + (size_t)l * NTYPE * DIM * DIM;
        const float* Wv_l = Wv + (size_t)l * NTYPE * DIM * DIM;
        const float* Wa_l = Wa + (size_t)l * NTYPE * DIM * DIM;
        const float* ratt_l = ratt + (size_t)l * NHEAD * NREL * HDIM * HDIM;
        const float* rmsg_l = rmsg + (size_t)l * NHEAD * NREL * HDIM * HDIM;
        const float* rpri_l = rpri + (size_t)l * NHEAD * NREL;
        const float* skip_l = skip + (size_t)l * NTYPE;
        const float* g_l = ln_g + (size_t)l * DIM;
        const float* b_l = ln_b + (size_t)l * DIM;

        k_qkv_g<<<NGB, 128, 0, stream>>>(h, perm, ntype, Wk_l, Wq_l, Wv_l,
                                         kbuf, qbuf, vbuf, N_NODES);
        k_fused2<<<N_NODES, 128, 0, stream>>>(kbuf, qbuf, vbuf, rs2, esrc,
                                              ratt_l, rmsg_l, rpri_l, agg);
        k_out_g<<<NGB, 128, 0, stream>>>(agg, h, perm, ntype, Wa_l, skip_l, g_l, b_l, N_NODES);
    }
}

// Round 4
// 1040.965 us; speedup vs baseline: 1.3568x; 1.3568x over previous
//
#include <hip/hip_runtime.h>
#include <math.h>

#define N_NODES 50000
#define DIM     128
#define NHEAD   8
#define HDIM    16
#define NLAYER  2
#define NTYPE   4
#define NREL    8
#define NEDGE   800000
#define RB      256
#define GN      8      // nodes per block in grouped qkv/out kernels
#define NK      (N_NODES * NREL)   // (dst,etype) buckets
#define WMAX    128    // edges per super-round in fused kernel

// ================= init: rank within type =================

__global__ void k_hist(const int* __restrict__ ntype, int* __restrict__ hist, int n) {
    __shared__ int cnt[NTYPE];
    if (threadIdx.x < NTYPE) cnt[threadIdx.x] = 0;
    __syncthreads();
    int i = blockIdx.x * RB + threadIdx.x;
    if (i < n) atomicAdd(&cnt[ntype[i]], 1);
    __syncthreads();
    if (threadIdx.x < NTYPE) hist[blockIdx.x * NTYPE + threadIdx.x] = cnt[threadIdx.x];
}

__global__ void k_prefix(const int* __restrict__ hist, int* __restrict__ off, int nb) {
    int t = threadIdx.x;
    if (t >= NTYPE) return;
    int acc = 0;
    for (int b = 0; b < nb; b++) { off[b * NTYPE + t] = acc; acc += hist[b * NTYPE + t]; }
}

__global__ void k_rank(const int* __restrict__ ntype, const int* __restrict__ off,
                       int* __restrict__ rank, int n) {
    __shared__ int ty[RB];
    int i = blockIdx.x * RB + threadIdx.x;
    int t = (i < n) ? ntype[i] : -1;
    ty[threadIdx.x] = t;
    __syncthreads();
    if (i < n) {
        int c = 0;
        for (int j = 0; j < (int)threadIdx.x; j++) c += (ty[j] == t);
        rank[i] = off[blockIdx.x * NTYPE + t] + c;
    }
}

__global__ void k_embed(const float* __restrict__ embed, const int* __restrict__ ntype,
                        const int* __restrict__ rank, float* __restrict__ h) {
    int i = blockIdx.x;
    int t = ntype[i], r = rank[i];
    h[(size_t)i * DIM + threadIdx.x] = embed[((size_t)t * N_NODES + r) * DIM + threadIdx.x];
}

__global__ void k_typeoff(const int* __restrict__ hist, const int* __restrict__ boff,
                          int nb, int* __restrict__ typeoff) {
    if (threadIdx.x == 0 && blockIdx.x == 0) {
        int acc = 0;
        for (int t = 0; t < NTYPE; t++) {
            typeoff[t] = acc;
            acc += boff[(nb - 1) * NTYPE + t] + hist[(nb - 1) * NTYPE + t];
        }
    }
}

__global__ void k_perm(const int* __restrict__ ntype, const int* __restrict__ rank,
                       const int* __restrict__ typeoff, int* __restrict__ perm, int n) {
    int i = blockIdx.x * 256 + threadIdx.x;
    if (i < n) perm[typeoff[ntype[i]] + rank[i]] = i;
}

// ================= (dst,etype)-sorted CSR build =================

__global__ void k_deg2(const int* __restrict__ dst, const int* __restrict__ etype,
                       int* __restrict__ deg) {
    int e = blockIdx.x * 256 + threadIdx.x;
    if (e < NEDGE) atomicAdd(&deg[dst[e] * NREL + etype[e]], 1);
}

__global__ void k_scan1(const int* __restrict__ deg, int* __restrict__ rs,
                        int* __restrict__ bsum, int n) {
    __shared__ int sh[256];
    int i = blockIdx.x * 256 + threadIdx.x;
    int v = (i < n) ? deg[i] : 0;
    sh[threadIdx.x] = v;
    __syncthreads();
    for (int off = 1; off < 256; off <<= 1) {
        int x = (threadIdx.x >= off) ? sh[threadIdx.x - off] : 0;
        __syncthreads();
        sh[threadIdx.x] += x;
        __syncthreads();
    }
    if (i < n) rs[i] = sh[threadIdx.x] - v;
    if (threadIdx.x == 255) bsum[blockIdx.x] = sh[255];
}

__global__ void k_scan2b(int* __restrict__ bsum, int nb) {
    __shared__ int sh[256];
    __shared__ int carry;
    if (threadIdx.x == 0) carry = 0;
    __syncthreads();
    for (int base = 0; base < nb; base += 256) {
        int i = base + threadIdx.x;
        int v = (i < nb) ? bsum[i] : 0;
        sh[threadIdx.x] = v;
        __syncthreads();
        for (int off = 1; off < 256; off <<= 1) {
            int x = (threadIdx.x >= off) ? sh[threadIdx.x - off] : 0;
            __syncthreads();
            sh[threadIdx.x] += x;
            __syncthreads();
        }
        if (i < nb) bsum[i] = sh[threadIdx.x] - v + carry;
        __syncthreads();
        if (threadIdx.x == 0) carry += sh[255];
        __syncthreads();
    }
}

__global__ void k_scan3(int* __restrict__ rs, const int* __restrict__ bsum, int n) {
    int i = blockIdx.x * 256 + threadIdx.x;
    if (i < n) rs[i] += bsum[blockIdx.x];
    if (i == 0) rs[n] = NEDGE;
}

// pack src | (etype<<24) so the fused kernel gets both in one load
__global__ void k_scatter2(const int* __restrict__ src, const int* __restrict__ dst,
                           const int* __restrict__ etype, const int* __restrict__ rs,
                           int* __restrict__ cur, int* __restrict__ epk) {
    int e = blockIdx.x * 256 + threadIdx.x;
    if (e < NEDGE) {
        int et = etype[e];
        int key = dst[e] * NREL + et;
        int p = atomicAdd(&cur[key], 1);
        epk[rs[key] + p] = src[e] | (et << 24);
    }
}

// ================= typed k/q/v projection, 8 same-type nodes/block =================

__global__ __launch_bounds__(128) void k_qkv_g(
        const float* __restrict__ h, const int* __restrict__ perm, const int* __restrict__ ntype,
        const float* __restrict__ Wk, const float* __restrict__ Wq, const float* __restrict__ Wv,
        float* __restrict__ kout, float* __restrict__ qout, float* __restrict__ vout, int n) {
    int o = threadIdx.x;
    int base = blockIdx.x * GN;
    __shared__ float xs[GN][DIM];
    __shared__ int nodes[GN];
    __shared__ int types[GN];
    if (o < GN) {
        int idx = base + o;
        int nd = (idx < n) ? perm[idx] : -1;
        nodes[o] = nd;
        types[o] = (nd >= 0) ? ntype[nd] : -1;
    }
    __syncthreads();
    #pragma unroll
    for (int nn = 0; nn < GN; nn++)
        if (nodes[nn] >= 0) xs[nn][o] = h[(size_t)nodes[nn] * DIM + o];
    __syncthreads();
    bool same = (nodes[GN - 1] >= 0) && (types[0] == types[GN - 1]);
    if (same) {
        int t = types[0];
        const float* wk = Wk + (size_t)t * DIM * DIM;
        const float* wq = Wq + (size_t)t * DIM * DIM;
        const float* wv = Wv + (size_t)t * DIM * DIM;
        float ak[GN], aq[GN], av[GN];
        #pragma unroll
        for (int nn = 0; nn < GN; nn++) { ak[nn] = 0.f; aq[nn] = 0.f; av[nn] = 0.f; }
        for (int d = 0; d < DIM; d++) {
            float wkv = wk[d * DIM + o], wqv = wq[d * DIM + o], wvv = wv[d * DIM + o];
            #pragma unroll
            for (int nn = 0; nn < GN; nn++) {
                float xv = xs[nn][d];
                ak[nn] = fmaf(xv, wkv, ak[nn]);
                aq[nn] = fmaf(xv, wqv, aq[nn]);
                av[nn] = fmaf(xv, wvv, av[nn]);
            }
        }
        #pragma unroll
        for (int nn = 0; nn < GN; nn++) {
            size_t p = (size_t)nodes[nn] * DIM + o;
            kout[p] = ak[nn]; qout[p] = aq[nn]; vout[p] = av[nn];
        }
    } else {
        #pragma unroll
        for (int nn = 0; nn < GN; nn++) {
            if (nodes[nn] < 0) continue;
            int t = types[nn];
            const float* wk = Wk + (size_t)t * DIM * DIM;
            const float* wq = Wq + (size_t)t * DIM * DIM;
            const float* wv = Wv + (size_t)t * DIM * DIM;
            float ak = 0.f, aq = 0.f, av = 0.f;
            for (int d = 0; d < DIM; d++) {
                float xv = xs[nn][d];
                ak = fmaf(xv, wk[d * DIM + o], ak);
                aq = fmaf(xv, wq[d * DIM + o], aq);
                av = fmaf(xv, wv[d * DIM + o], av);
            }
            size_t p = (size_t)nodes[nn] * DIM + o;
            kout[p] = ak; aq; av;
            kout[p] = ak; qout[p] = aq; vout[p] = av;
        }
    }
}

// ================= fused attention v3: decoupled softmax, register buckets =================
// Block = 128 threads = one dst node. thread (hh = tid>>4, oo = tid&15).
// Pass1: chunked logits -> LDS, running max (no shfl), one reduce + exp sweep.
// Pass2: et-outer (unrolled, B[8] registers), per-edge {2 LDS broadcasts + coalesced v + FMA}.
// Single W_msg apply at the end. Super-rounds (WMAX) keep deg>128 correct.

__global__ __launch_bounds__(128) void k_fused3(
        const float* __restrict__ kbuf, const float* __restrict__ qbuf, const float* __restrict__ vbuf,
        const int* __restrict__ rs2, const int* __restrict__ epk,
        const float* __restrict__ ratt, const float* __restrict__ rmsg, const float* __restrict__ rpri,
        float* __restrict__ agg) {
    int node = blockIdx.x;
    int tid = threadIdx.x;
    int hh = tid >> 4, oo = tid & 15;
    int gbase = tid & 0x30;            // 16-lane group base within the wave

    __shared__ float q_s[DIM];
    __shared__ float u_s[NREL][NHEAD][HDIM + 1];  // +1: spread et across banks
    __shared__ float a_s[NHEAD][WMAX + 1];        // +1: spread hh across banks
    __shared__ int   es_s[WMAX];
    __shared__ int   rs_s[NREL + 1];

    q_s[tid] = qbuf[(size_t)node * DIM + tid];
    if (tid <= NREL) rs_s[tid] = rs2[node * NREL + tid];
    __syncthreads();

    int e0 = rs_s[0], e1 = rs_s[NREL];

    // q row for this head into registers (LDS broadcast reads, once)
    float qr[HDIM];
    #pragma unroll
    for (int j = 0; j < HDIM; j++) qr[j] = q_s[hh * HDIM + j];

    // u_s[et][hh][d] = (ratt[hh][et][d][:] . q_h) * pri * 0.25, for present etypes
    #pragma unroll
    for (int et = 0; et < NREL; et++) {
        if (rs_s[et] < rs_s[et + 1]) {
            const float4* w4 = (const float4*)(ratt + ((size_t)(hh * NREL + et) * HDIM + oo) * HDIM);
            float4 w0 = w4[0], w1 = w4[1], w2 = w4[2], w3 = w4[3];
            float s = w0.x * qr[0] + w0.y * qr[1] + w0.z * qr[2] + w0.w * qr[3]
                    + w1.x * qr[4] + w1.y * qr[5] + w1.z * qr[6] + w1.w * qr[7]
                    + w2.x * qr[8] + w2.y * qr[9] + w2.z * qr[10] + w2.w * qr[11]
                    + w3.x * qr[12] + w3.y * qr[13] + w3.z * qr[14] + w3.w * qr[15];
            u_s[et][hh][oo] = s * rpri[hh * NREL + et] * 0.25f;
        }
    }
    // u_s written/read by same 16-lane group only -> no barrier needed

    float B[NREL];
    #pragma unroll
    for (int et = 0; et < NREL; et++) B[et] = 0.f;
    float m_h = -1e30f, s_h = 0.f;

    for (int w0 = e0; w0 < e1; w0 += WMAX) {
        int wcnt = min(WMAX, e1 - w0);
        // ---- pass 1: logits -> a_s, per-lane running max ----
        float mloc = -1e30f;
        for (int base = 0; base < wcnt; base += 16) {
            int c = base + oo;
            if (c < wcnt) {
                int pk = epk[w0 + c];
                int sv = pk & 0x00FFFFFF;
                int et = ((unsigned)pk) >> 24;
                if (hh == 0) es_s[c] = sv;
                const float4* kr = (const float4*)(kbuf + (size_t)sv * DIM + hh * HDIM);
                float4 k0 = kr[0], k1 = kr[1], k2 = kr[2], k3 = kr[3];
                const float* u = &u_s[et][hh][0];
                float a = k0.x * u[0] + k0.y * u[1] + k0.z * u[2] + k0.w * u[3]
                        + k1.x * u[4] + k1.y * u[5] + k1.z * u[6] + k1.w * u[7]
                        + k2.x * u[8] + k2.y * u[9] + k2.z * u[10] + k2.w * u[11]
                        + k3.x * u[12] + k3.y * u[13] + k3.z * u[14] + k3.w * u[15];
                a_s[hh][c] = a;
                mloc = fmaxf(mloc, a);
            }
        }
        // group max reduce (once per round)
        mloc = fmaxf(mloc, __shfl_xor(mloc, 1));
        mloc = fmaxf(mloc, __shfl_xor(mloc, 2));
        mloc = fmaxf(mloc, __shfl_xor(mloc, 4));
        mloc = fmaxf(mloc, __shfl_xor(mloc, 8));
        float m_new = fmaxf(m_h, mloc);
        float r = __expf(m_h - m_new);   // 0 on first round
        s_h *= r;
        #pragma unroll
        for (int et = 0; et < NREL; et++) B[et] *= r;
        m_h = m_new;
        // exp sweep + sum (a_s within-group -> no barrier yet)
        float ssum = 0.f;
        for (int c = oo; c < wcnt; c += 16) {
            float p = __expf(a_s[hh][c] - m_new);
            a_s[hh][c] = p;
            ssum += p;
        }
        ssum += __shfl_xor(ssum, 1);
        ssum += __shfl_xor(ssum, 2);
        ssum += __shfl_xor(ssum, 4);
        ssum += __shfl_xor(ssum, 8);
        s_h += ssum;
        __syncthreads();   // es_s (wave0) visible to wave1
        // ---- pass 2: et-outer register-bucket v accumulation ----
        #pragma unroll
        for (int et = 0; et < NREL; et++) {
            int s0 = max(rs_s[et], w0) - w0;
            int s1 = min(rs_s[et + 1], w0 + wcnt) - w0;
            float acc = 0.f;
            for (int c = s0; c < s1; c++) {
                float p = a_s[hh][c];               // broadcast within group
                int   sv = es_s[c];                 // broadcast across block
                acc = fmaf(p, vbuf[(size_t)sv * DIM + tid], acc);  // coalesced
            }
            B[et] += acc;
        }
        __syncthreads();   // protect es_s/a_s before next round overwrites
    }

    // ---- single W_msg apply: out[hh][oo] = sum_et sum_d B[et][d] * W[hh][et][d][oo] ----
    float out = 0.f;
    #pragma unroll
    for (int et = 0; et < NREL; et++) {
        if (rs_s[et] < rs_s[et + 1]) {
            const float* w = rmsg + (size_t)(hh * NREL + et) * HDIM * HDIM;
            #pragma unroll
            for (int d = 0; d < HDIM; d++) {
                float bd = __shfl(B[et], gbase | d);
                out = fmaf(bd, w[d * HDIM + oo], out);
            }
        }
    }
    agg[(size_t)node * DIM + tid] = out / (s_h + 1e-9f);
}

// ================= output projection + skip + LayerNorm + residual, grouped =================

__global__ __launch_bounds__(128) void k_out_g(
        const float* __restrict__ agg, float* __restrict__ h,
        const int* __restrict__ perm, const int* __restrict__ ntype,
        const float* __restrict__ Wa, const float* __restrict__ skip,
        const float* __restrict__ ln_g, const float* __restrict__ ln_b, int n) {
    int o = threadIdx.x;
    int base = blockIdx.x * GN;
    __shared__ float xs[GN][DIM];
    __shared__ float hcs[GN][DIM + 1];
    __shared__ int nodes[GN];
    __shared__ int types[GN];
    __shared__ float mu_s[GN], rs_s[GN];
    if (o < GN) {
        int idx = base + o;
        int nd = (idx < n) ? perm[idx] : -1;
        nodes[o] = nd;
        types[o] = (nd >= 0) ? ntype[nd] : -1;
    }
    __syncthreads();
    #pragma unroll
    for (int nn = 0; nn < GN; nn++)
        if (nodes[nn] >= 0) xs[nn][o] = agg[(size_t)nodes[nn] * DIM + o];
    __syncthreads();
    bool same = (nodes[GN - 1] >= 0) && (types[0] == types[GN - 1]);
    if (same) {
        int t = types[0];
        const float* w = Wa + (size_t)t * DIM * DIM;
        float acc[GN];
        #pragma unroll
        for (int nn = 0; nn < GN; nn++) acc[nn] = 0.f;
        for (int d = 0; d < DIM; d++) {
            float wv = w[d * DIM + o];
            #pragma unroll
            for (int nn = 0; nn < GN; nn++) acc[nn] = fmaf(xs[nn][d], wv, acc[nn]);
        }
        float alpha = 1.f / (1.f + __expf(-skip[t]));
        #pragma unroll
        for (int nn = 0; nn < GN; nn++) {
            float hp = h[(size_t)nodes[nn] * DIM + o];
            hcs[nn][o] = acc[nn] * alpha + hp * (1.f - alpha);
        }
    } else {
        #pragma unroll
        for (int nn = 0; nn < GN; nn++) {
            if (nodes[nn] < 0) continue;
            int t = types[nn];
            const float* w = Wa + (size_t)t * DIM * DIM;
            float a0 = 0.f;
            for (int d = 0; d < DIM; d++) a0 = fmaf(xs[nn][d], w[d * DIM + o], a0);
            float alpha = 1.f / (1.f + __expf(-skip[t]));
            float hp = h[(size_t)nodes[nn] * DIM + o];
            hcs[nn][o] = a0 * alpha + hp * (1.f - alpha);
        }
    }
    __syncthreads();
    {
        int g = o >> 4, j = o & 15;
        if (nodes[g] >= 0) {
            float s = 0.f;
            for (int d = j; d < DIM; d += 16) s += hcs[g][d];
            #pragma unroll
            for (int m = 1; m < 16; m <<= 1) s += __shfl_xor(s, m);
            float mu = s * (1.f / DIM);
            float v = 0.f;
            for (int d = j; d < DIM; d += 16) { float dv = hcs[g][d] - mu; v = fmaf(dv, dv, v); }
            #pragma unroll
            for (int m = 1; m < 16; m <<= 1) v += __shfl_xor(v, m);
            if (j == 0) { mu_s[g] = mu; rs_s[g] = rsqrtf(v * (1.f / DIM) + 1e-5f); }
        }
    }
    __syncthreads();
    float g_o = ln_g[o], b_o = ln_b[o];
    #pragma unroll
    for (int nn = 0; nn < GN; nn++) {
        if (nodes[nn] >= 0) {
            float hp = h[(size_t)nodes[nn] * DIM + o];
            h[(size_t)nodes[nn] * DIM + o] = (hcs[nn][o] - mu_s[nn]) * rs_s[nn] * g_o + b_o + hp;
        }
    }
}

// ================= host =================

extern "C" void kernel_launch(void* const* d_in, const int* in_sizes, int n_in,
                              void* d_out, int out_size, void* d_ws, size_t ws_size,
                              hipStream_t stream) {
    const float* embed = (const float*)d_in[0];
    const float* Wk    = (const float*)d_in[1];
    const float* Wq    = (const float*)d_in[2];
    const float* Wv    = (const float*)d_in[3];
    const float* Wa    = (const float*)d_in[4];
    const float* ratt  = (const float*)d_in[5];
    const float* rmsg  = (const float*)d_in[6];
    const float* rpri  = (const float*)d_in[7];
    const float* skip  = (const float*)d_in[8];
    const float* ln_g  = (const float*)d_in[9];
    const float* ln_b  = (const float*)d_in[10];
    const int*   src   = (const int*)d_in[11];
    const int*   dst   = (const int*)d_in[12];
    const int*   ntype = (const int*)d_in[13];
    const int*   etype = (const int*)d_in[14];

    float* h = (float*)d_out;

    const size_t ND = (size_t)N_NODES * DIM;
    float* kbuf = (float*)d_ws;
    float* qbuf = kbuf + ND;
    float* vbuf = qbuf + ND;
    int* rs2  = (int*)(vbuf + ND);               // NK+1
    int* deg2 = rs2 + (NK + 1);                  // NK
    int* cur2 = deg2 + NK;                       // NK
    int* epk  = cur2 + NK;                       // E (packed src|et<<24)
    int* bsum = epk + NEDGE;                     // 2048
    int* rank = bsum + 2048;                     // N
    const int nb = (N_NODES + RB - 1) / RB;
    int* hist = rank + N_NODES;                  // nb*NTYPE
    int* boff = hist + nb * NTYPE;               // nb*NTYPE
    int* typeoff = boff + nb * NTYPE;            // NTYPE
    int* perm = typeoff + NTYPE;                 // N
    float* agg = qbuf;                           // alias: q dead once fused block read its row

    const int EB = (NEDGE + 255) / 256;
    const int nb2 = (NK + 255) / 256;

    // ---- init: rank-within-type, embedding, type permutation ----
    k_hist<<<nb, RB, 0, stream>>>(ntype, hist, N_NODES);
    k_prefix<<<1, 64, 0, stream>>>(hist, boff, nb);
    k_rank<<<nb, RB, 0, stream>>>(ntype, boff, rank, N_NODES);
    k_embed<<<N_NODES, DIM, 0, stream>>>(embed, ntype, rank, h);
    k_typeoff<<<1, 64, 0, stream>>>(hist, boff, nb, typeoff);
    k_perm<<<nb, 256, 0, stream>>>(ntype, rank, typeoff, perm, N_NODES);

    // ---- (dst,etype)-sorted CSR build (once; graph static across layers) ----
    hipMemsetAsync(deg2, 0, (size_t)NK * sizeof(int), stream);
    hipMemsetAsync(cur2, 0, (size_t)NK * sizeof(int), stream);
    k_deg2<<<EB, 256, 0, stream>>>(dst, etype, deg2);
    k_scan1<<<nb2, 256, 0, stream>>>(deg2, rs2, bsum, NK);
    k_scan2b<<<1, 256, 0, stream>>>(bsum, nb2);
    k_scan3<<<nb2, 256, 0, stream>>>(rs2, bsum, NK);
    k_scatter2<<<EB, 256, 0, stream>>>(src, dst, etype, rs2, cur2, epk);

    const int NGB = N_NODES / GN;

    for (int l = 0; l < NLAYER; l++) {
        const float* Wk_l = Wk + (size_t)l * NTYPE * DIM * DIM;
        const float* Wq_l = Wq + (size_t)l * NTYPE * DIM * DIM;
        const float* Wv_l = Wv + (size_t)l * NTYPE * DIM * DIM;
        const float* Wa_l = Wa + (size_t)l * NTYPE * DIM * DIM;
        const float* ratt_l = ratt + (size_t)l * NHEAD * NREL * HDIM * HDIM;
        const float* rmsg_l = rmsg + (size_t)l * NHEAD * NREL * HDIM * HDIM;
        const float* rpri_l = rpri + (size_t)l * NHEAD * NREL;
        const float* skip_l = skip + (size_t)l * NTYPE;
        const float* g_l = ln_g + (size_t)l * DIM;
        const float* b_l = ln_b + (size_t)l * DIM;

        k_qkv_g<<<NGB, 128, 0, stream>>>(h, perm, ntype, Wk_l, Wq_l, Wv_l,
                                         kbuf, qbuf, vbuf, N_NODES);
        k_fused3<<<N_NODES, 128, 0, stream>>>(kbuf, qbuf, vbuf, rs2, epk,
                                              ratt_l, rmsg_l, rpri_l, agg);
        k_out_g<<<NGB, 128, 0, stream>>>(agg, h, perm, ntype, Wa_l, skip_l, g_l, b_l, N_NODES);
    }
}

// Round 5
// 1001.207 us; speedup vs baseline: 1.4106x; 1.0397x over previous
//
#include <hip/hip_runtime.h>
#include <math.h>

#define N_NODES 50000
#define DIM     128
#define NHEAD   8
#define HDIM    16
#define NLAYER  2
#define NTYPE   4
#define NREL    8
#define NEDGE   800000
#define RB      256
#define GN      8      // nodes per block in grouped qkv/out/vt kernels
#define NK      (N_NODES * NREL)   // (dst,etype) buckets
#define WMAX    128    // edges per super-round in fused kernel

// ================= init: rank within type =================

__global__ void k_hist(const int* __restrict__ ntype, int* __restrict__ hist, int n) {
    __shared__ int cnt[NTYPE];
    if (threadIdx.x < NTYPE) cnt[threadIdx.x] = 0;
    __syncthreads();
    int i = blockIdx.x * RB + threadIdx.x;
    if (i < n) atomicAdd(&cnt[ntype[i]], 1);
    __syncthreads();
    if (threadIdx.x < NTYPE) hist[blockIdx.x * NTYPE + threadIdx.x] = cnt[threadIdx.x];
}

__global__ void k_prefix(const int* __restrict__ hist, int* __restrict__ off, int nb) {
    int t = threadIdx.x;
    if (t >= NTYPE) return;
    int acc = 0;
    for (int b = 0; b < nb; b++) { off[b * NTYPE + t] = acc; acc += hist[b * NTYPE + t]; }
}

__global__ void k_rank(const int* __restrict__ ntype, const int* __restrict__ off,
                       int* __restrict__ rank, int n) {
    __shared__ int ty[RB];
    int i = blockIdx.x * RB + threadIdx.x;
    int t = (i < n) ? ntype[i] : -1;
    ty[threadIdx.x] = t;
    __syncthreads();
    if (i < n) {
        int c = 0;
        for (int j = 0; j < (int)threadIdx.x; j++) c += (ty[j] == t);
        rank[i] = off[blockIdx.x * NTYPE + t] + c;
    }
}

__global__ void k_embed(const float* __restrict__ embed, const int* __restrict__ ntype,
                        const int* __restrict__ rank, float* __restrict__ h) {
    int i = blockIdx.x;
    int t = ntype[i], r = rank[i];
    h[(size_t)i * DIM + threadIdx.x] = embed[((size_t)t * N_NODES + r) * DIM + threadIdx.x];
}

__global__ void k_typeoff(const int* __restrict__ hist, const int* __restrict__ boff,
                          int nb, int* __restrict__ typeoff) {
    if (threadIdx.x == 0 && blockIdx.x == 0) {
        int acc = 0;
        for (int t = 0; t < NTYPE; t++) {
            typeoff[t] = acc;
            acc += boff[(nb - 1) * NTYPE + t] + hist[(nb - 1) * NTYPE + t];
        }
    }
}

__global__ void k_perm(const int* __restrict__ ntype, const int* __restrict__ rank,
                       const int* __restrict__ typeoff, int* __restrict__ perm, int n) {
    int i = blockIdx.x * 256 + threadIdx.x;
    if (i < n) perm[typeoff[ntype[i]] + rank[i]] = i;
}

// ================= (dst,etype)-sorted CSR build =================

__global__ void k_deg2(const int* __restrict__ dst, const int* __restrict__ etype,
                       int* __restrict__ deg) {
    int e = blockIdx.x * 256 + threadIdx.x;
    if (e < NEDGE) atomicAdd(&deg[dst[e] * NREL + etype[e]], 1);
}

__global__ void k_scan1(const int* __restrict__ deg, int* __restrict__ rs,
                        int* __restrict__ bsum, int n) {
    __shared__ int sh[256];
    int i = blockIdx.x * 256 + threadIdx.x;
    int v = (i < n) ? deg[i] : 0;
    sh[threadIdx.x] = v;
    __syncthreads();
    for (int off = 1; off < 256; off <<= 1) {
        int x = (threadIdx.x >= off) ? sh[threadIdx.x - off] : 0;
        __syncthreads();
        sh[threadIdx.x] += x;
        __syncthreads();
    }
    if (i < n) rs[i] = sh[threadIdx.x] - v;
    if (threadIdx.x == 255) bsum[blockIdx.x] = sh[255];
}

__global__ void k_scan2b(int* __restrict__ bsum, int nb) {
    __shared__ int sh[256];
    __shared__ int carry;
    if (threadIdx.x == 0) carry = 0;
    __syncthreads();
    for (int base = 0; base < nb; base += 256) {
        int i = base + threadIdx.x;
        int v = (i < nb) ? bsum[i] : 0;
        sh[threadIdx.x] = v;
        __syncthreads();
        for (int off = 1; off < 256; off <<= 1) {
            int x = (threadIdx.x >= off) ? sh[threadIdx.x - off] : 0;
            __syncthreads();
            sh[threadIdx.x] += x;
            __syncthreads();
        }
        if (i < nb) bsum[i] = sh[threadIdx.x] - v + carry;
        __syncthreads();
        if (threadIdx.x == 0) carry += sh[255];
        __syncthreads();
    }
}

__global__ void k_scan3(int* __restrict__ rs, const int* __restrict__ bsum, int n) {
    int i = blockIdx.x * 256 + threadIdx.x;
    if (i < n) rs[i] += bsum[blockIdx.x];
    if (i == 0) rs[n] = NEDGE;
}

// pack src | (etype<<24)
__global__ void k_scatter2(const int* __restrict__ src, const int* __restrict__ dst,
                           const int* __restrict__ etype, const int* __restrict__ rs,
                           int* __restrict__ cur, int* __restrict__ epk) {
    int e = blockIdx.x * 256 + threadIdx.x;
    if (e < NEDGE) {
        int et = etype[e];
        int key = dst[e] * NREL + et;
        int p = atomicAdd(&cur[key], 1);
        epk[rs[key] + p] = src[e] | (et << 24);
    }
}

// ================= rmsg transpose: rmsgT[l][h][et][o][d] = rmsg[l][h][et][d][o] ====

__global__ void k_rmsgT(const float* __restrict__ rmsg, float* __restrict__ rmsgT) {
    int b = blockIdx.x;                 // (l, h, et) flattened
    int d = threadIdx.x >> 4, o = threadIdx.x & 15;
    rmsgT[b * 256 + o * 16 + d] = rmsg[b * 256 + d * 16 + o];
}

// ================= typed k/q/v projection, 8 same-type nodes/block =================

__global__ __launch_bounds__(128) void k_qkv_g(
        const float* __restrict__ h, const int* __restrict__ perm, const int* __restrict__ ntype,
        const float* __restrict__ Wk, const float* __restrict__ Wq, const float* __restrict__ Wv,
        float* __restrict__ kout, float* __restrict__ qout, float* __restrict__ vout, int n) {
    int o = threadIdx.x;
    int base = blockIdx.x * GN;
    __shared__ float xs[GN][DIM];
    __shared__ int nodes[GN];
    __shared__ int types[GN];
    if (o < GN) {
        int idx = base + o;
        int nd = (idx < n) ? perm[idx] : -1;
        nodes[o] = nd;
        types[o] = (nd >= 0) ? ntype[nd] : -1;
    }
    __syncthreads();
    #pragma unroll
    for (int nn = 0; nn < GN; nn++)
        if (nodes[nn] >= 0) xs[nn][o] = h[(size_t)nodes[nn] * DIM + o];
    __syncthreads();
    bool same = (nodes[GN - 1] >= 0) && (types[0] == types[GN - 1]);
    if (same) {
        int t = types[0];
        const float* wk = Wk + (size_t)t * DIM * DIM;
        const float* wq = Wq + (size_t)t * DIM * DIM;
        const float* wv = Wv + (size_t)t * DIM * DIM;
        float ak[GN], aq[GN], av[GN];
        #pragma unroll
        for (int nn = 0; nn < GN; nn++) { ak[nn] = 0.f; aq[nn] = 0.f; av[nn] = 0.f; }
        for (int d = 0; d < DIM; d++) {
            float wkv = wk[d * DIM + o], wqv = wq[d * DIM + o], wvv = wv[d * DIM + o];
            #pragma unroll
            for (int nn = 0; nn < GN; nn++) {
                float xv = xs[nn][d];
                ak[nn] = fmaf(xv, wkv, ak[nn]);
                aq[nn] = fmaf(xv, wqv, aq[nn]);
                av[nn] = fmaf(xv, wvv, av[nn]);
            }
        }
        #pragma unroll
        for (int nn = 0; nn < GN; nn++) {
            size_t p = (size_t)nodes[nn] * DIM + o;
            kout[p] = ak[nn]; qout[p] = aq[nn]; vout[p] = av[nn];
        }
    } else {
        #pragma unroll
        for (int nn = 0; nn < GN; nn++) {
            if (nodes[nn] < 0) continue;
            int t = types[nn];
            const float* wk = Wk + (size_t)t * DIM * DIM;
            const float* wq = Wq + (size_t)t * DIM * DIM;
            const float* wv = Wv + (size_t)t * DIM * DIM;
            float ak = 0.f, aq = 0.f, av = 0.f;
            for (int d = 0; d < DIM; d++) {
                float xv = xs[nn][d];
                ak = fmaf(xv, wk[d * DIM + o], ak);
                aq = fmaf(xv, wq[d * DIM + o], aq);
                av = fmaf(xv, wv[d * DIM + o], av);
            }
            size_t p = (size_t)nodes[nn] * DIM + o;
            kout[p] = ak; qout[p] = aq; vout[p] = av;
        }
    }
}

// ================= vt build: vt[n][et][h*16+o] = bf16( sum_d v[n][h*16+d] * rmsg[h][et][d][o] ) ==

__global__ __launch_bounds__(128) void k_vt(
        const float* __restrict__ vbuf, const float* __restrict__ rmsgT,
        unsigned short* __restrict__ vt) {
    int tid = threadIdx.x;
    int hh = tid >> 4, oo = tid & 15;
    int base = blockIdx.x * GN;
    __shared__ float v_s[GN][DIM];
    #pragma unroll
    for (int nn = 0; nn < GN; nn++)
        v_s[nn][tid] = vbuf[(size_t)(base + nn) * DIM + tid];
    __syncthreads();
    #pragma unroll 1
    for (int et = 0; et < NREL; et++) {
        const float4* w4 = (const float4*)(rmsgT + ((size_t)(hh * NREL + et) * HDIM + oo) * HDIM);
        float4 w0 = w4[0], w1 = w4[1], w2 = w4[2], w3 = w4[3];
        #pragma unroll
        for (int nn = 0; nn < GN; nn++) {
            const float4* v4 = (const float4*)&v_s[nn][hh * HDIM];
            float4 v0 = v4[0], v1 = v4[1], v2 = v4[2], v3 = v4[3];
            float acc = v0.x*w0.x + v0.y*w0.y + v0.z*w0.z + v0.w*w0.w
                      + v1.x*w1.x + v1.y*w1.y + v1.z*w1.z + v1.w*w1.w
                      + v2.x*w2.x + v2.y*w2.y + v2.z*w2.z + v2.w*w2.w
                      + v3.x*w3.x + v3.y*w3.y + v3.z*w3.z + v3.w*w3.w;
            unsigned b = __float_as_uint(acc);
            b += 0x7FFFu + ((b >> 16) & 1u);        // RNE to bf16
            vt[((size_t)(base + nn) * NREL + et) * DIM + tid] = (unsigned short)(b >> 16);
        }
    }
}

// ================= fused attention v4 =================
// Block = 128 threads = one dst node. thread (hh = tid>>4, oo = tid&15).
// MODE 0: message via precomputed vt (bf16), single running out register.
// MODE 1: register et-buckets + LDS b128 flush (no ds_bpermute) — fallback when ws small.
// No __syncthreads in the edge loop (all LDS comms intra-wave, in-order LDS pipe).

template<int MODE>
__global__ __launch_bounds__(128) void k_fused4(
        const float* __restrict__ kbuf, const float* __restrict__ qbuf,
        const float* __restrict__ vbuf, const unsigned short* __restrict__ vt,
        const int* __restrict__ rs2, const int* __restrict__ epk,
        const float* __restrict__ ratt, const float* __restrict__ rmsgT,
        const float* __restrict__ rpri, float* __restrict__ agg) {
    int node = blockIdx.x;
    int tid = threadIdx.x;
    int hh = tid >> 4, oo = tid & 15;

    __shared__ float q_s[DIM];
    __shared__ float u_s[NREL][NHEAD * HDIM + 4];   // stride 132: et rows 4 banks apart, 16B-aligned
    __shared__ float a_s[NHEAD][WMAX + 16];         // stride 144: head rows 16 banks apart
    __shared__ int rs_s[NREL + 1];

    q_s[tid] = qbuf[(size_t)node * DIM + tid];
    if (tid <= NREL) rs_s[tid] = rs2[node * NREL + tid];
    __syncthreads();

    int e0 = rs_s[0], e1 = rs_s[NREL];
    if (e0 == e1) { agg[(size_t)node * DIM + tid] = 0.f; return; }

    // u_s[et][hh*16+d] = (ratt[hh][et][d][:] . q_h) * pri * 0.25   (lane d = oo)
    {
        const float4* q4 = (const float4*)&q_s[hh * HDIM];
        float4 q0 = q4[0], q1 = q4[1], q2 = q4[2], q3 = q4[3];
        #pragma unroll
        for (int et = 0; et < NREL; et++) {
            if (rs_s[et] < rs_s[et + 1]) {
                const float4* w4 = (const float4*)(ratt + ((size_t)(hh * NREL + et) * HDIM + oo) * HDIM);
                float4 w0 = w4[0], w1 = w4[1], w2 = w4[2], w3 = w4[3];
                float s = w0.x*q0.x + w0.y*q0.y + w0.z*q0.z + w0.w*q0.w
                        + w1.x*q1.x + w1.y*q1.y + w1.z*q1.z + w1.w*q1.w
                        + w2.x*q2.x + w2.y*q2.y + w2.z*q2.z + w2.w*q2.w
                        + w3.x*q3.x + w3.y*q3.y + w3.z*q3.z + w3.w*q3.w;
                u_s[et][tid] = s * rpri[hh * NREL + et] * 0.25f;
            }
        }
    }
    __syncthreads();   // once per node; edge loop below is barrier-free

    float m_h = -1e30f, s_h = 0.f;
    float out = 0.f;        // MODE 0 accumulator
    float B[NREL];          // MODE 1 buckets
    #pragma unroll
    for (int et = 0; et < NREL; et++) B[et] = 0.f;

    for (int w0e = e0; w0e < e1; w0e += WMAX) {
        int wcnt = min(WMAX, e1 - w0e);
        // ---- pass 1: logits -> a_s, per-lane running max ----
        float mloc = -1e30f;
        for (int base = 0; base < wcnt; base += 16) {
            int c = base + oo;
            if (c < wcnt) {
                int pk = epk[w0e + c];
                int sv = pk & 0x00FFFFFF;
                int et = ((unsigned)pk) >> 24;
                const float4* kr = (const float4*)(kbuf + (size_t)sv * DIM + hh * HDIM);
                float4 k0 = kr[0], k1 = kr[1], k2 = kr[2], k3 = kr[3];
                const float4* u4 = (const float4*)&u_s[et][hh * HDIM];
                float4 u0 = u4[0], u1 = u4[1], u2 = u4[2], u3 = u4[3];
                float a = k0.x*u0.x + k0.y*u0.y + k0.z*u0.z + k0.w*u0.w
                        + k1.x*u1.x + k1.y*u1.y + k1.z*u1.z + k1.w*u1.w
                        + k2.x*u2.x + k2.y*u2.y + k2.z*u2.z + k2.w*u2.w
                        + k3.x*u3.x + k3.y*u3.y + k3.z*u3.z + k3.w*u3.w;
                a_s[hh][c] = a;
                mloc = fmaxf(mloc, a);
            }
        }
        mloc = fmaxf(mloc, __shfl_xor(mloc, 1));
        mloc = fmaxf(mloc, __shfl_xor(mloc, 2));
        mloc = fmaxf(mloc, __shfl_xor(mloc, 4));
        mloc = fmaxf(mloc, __shfl_xor(mloc, 8));
        float m_new = fmaxf(m_h, mloc);
        float r = __expf(m_h - m_new);     // 0 on first round
        s_h *= r;
        if constexpr (MODE == 0) {
            out *= r;
        } else {
            #pragma unroll
            for (int et = 0; et < NREL; et++) B[et] *= r;
        }
        m_h = m_new;
        float ssum = 0.f;
        for (int c = oo; c < wcnt; c += 16) {
            float p = __expf(a_s[hh][c] - m_new);
            a_s[hh][c] = p;
            ssum += p;
        }
        ssum += __shfl_xor(ssum, 1);
        ssum += __shfl_xor(ssum, 2);
        ssum += __shfl_xor(ssum, 4);
        ssum += __shfl_xor(ssum, 8);
        s_h += ssum;

        // ---- pass 2 ----
        if constexpr (MODE == 0) {
            for (int c = 0; c < wcnt; c++) {
                int pk = epk[w0e + c];                 // L1-hot broadcast
                int sv = pk & 0x00FFFFFF;
                int et = ((unsigned)pk) >> 24;
                float p = a_s[hh][c];                  // group broadcast
                unsigned short uv = vt[((size_t)sv * NREL + et) * DIM + tid];
                float v = __uint_as_float((unsigned)uv << 16);
                out = fmaf(p, v, out);
            }
        } else {
            #pragma unroll
            for (int et = 0; et < NREL; et++) {
                int s0 = max(rs_s[et], w0e);
                int s1 = min(rs_s[et + 1], w0e + wcnt);
                float acc = 0.f;
                for (int e = s0; e < s1; e++) {
                    int sv = epk[e] & 0x00FFFFFF;
                    acc = fmaf(a_s[hh][e - w0e], vbuf[(size_t)sv * DIM + tid], acc);
                }
                B[et] += acc;
            }
        }
    }

    float inv = 1.f / (s_h + 1e-9f);
    if constexpr (MODE == 0) {
        agg[(size_t)node * DIM + tid] = out * inv;
    } else {
        __syncthreads();
        float* B_s = &a_s[0][0];          // alias a_s (dead now); [et][128]
        #pragma unroll
        for (int et = 0; et < NREL; et++) B_s[et * DIM + tid] = B[et];
        __syncthreads();
        float o2 = 0.f;
        #pragma unroll
        for (int et = 0; et < NREL; et++) {
            if (rs_s[et] < rs_s[et + 1]) {
                const float4* w4 = (const float4*)(rmsgT + ((size_t)(hh * NREL + et) * HDIM + oo) * HDIM);
                float4 w0 = w4[0], w1 = w4[1], w2 = w4[2], w3 = w4[3];
                const float4* b4 = (const float4*)&B_s[et * DIM + hh * HDIM];
                float4 b0 = b4[0], b1 = b4[1], b2 = b4[2], b3 = b4[3];
                o2 += b0.x*w0.x + b0.y*w0.y + b0.z*w0.z + b0.w*w0.w
                    + b1.x*w1.x + b1.y*w1.y + b1.z*w1.z + b1.w*w1.w
                    + b2.x*w2.x + b2.y*w2.y + b2.z*w2.z + b2.w*w2.w
                    + b3.x*w3.x + b3.y*w3.y + b3.z*w3.z + b3.w*w3.w;
            }
        }
        agg[(size_t)node * DIM + tid] = o2 * inv;
    }
}

// ================= output projection + skip + LayerNorm + residual, grouped =================

__global__ __launch_bounds__(128) void k_out_g(
        const float* __restrict__ agg, float* __restrict__ h,
        const int* __restrict__ perm, const int* __restrict__ ntype,
        const float* __restrict__ Wa, const float* __restrict__ skip,
        const float* __restrict__ ln_g, const float* __restrict__ ln_b, int n) {
    int o = threadIdx.x;
    int base = blockIdx.x * GN;
    __shared__ float xs[GN][DIM];
    __shared__ float hcs[GN][DIM + 1];
    __shared__ int nodes[GN];
    __shared__ int types[GN];
    __shared__ float mu_s[GN], rs_s[GN];
    if (o < GN) {
        int idx = base + o;
        int nd = (idx < n) ? perm[idx] : -1;
        nodes[o] = nd;
        types[o] = (nd >= 0) ? ntype[nd] : -1;
    }
    __syncthreads();
    #pragma unroll
    for (int nn = 0; nn < GN; nn++)
        if (nodes[nn] >= 0) xs[nn][o] = agg[(size_t)nodes[nn] * DIM + o];
    __syncthreads();
    bool same = (nodes[GN - 1] >= 0) && (types[0] == types[GN - 1]);
    if (same) {
        int t = types[0];
        const float* w = Wa + (size_t)t * DIM * DIM;
        float acc[GN];
        #pragma unroll
        for (int nn = 0; nn < GN; nn++) acc[nn] = 0.f;
        for (int d = 0; d < DIM; d++) {
            float wv = w[d * DIM + o];
            #pragma unroll
            for (int nn = 0; nn < GN; nn++) acc[nn] = fmaf(xs[nn][d], wv, acc[nn]);
        }
        float alpha = 1.f / (1.f + __expf(-skip[t]));
        #pragma unroll
        for (int nn = 0; nn < GN; nn++) {
            float hp = h[(size_t)nodes[nn] * DIM + o];
            hcs[nn][o] = acc[nn] * alpha + hp * (1.f - alpha);
        }
    } else {
        #pragma unroll
        for (int nn = 0; nn < GN; nn++) {
            if (nodes[nn] < 0) continue;
            int t = types[nn];
            const float* w = Wa + (size_t)t * DIM * DIM;
            float a0 = 0.f;
            for (int d = 0; d < DIM; d++) a0 = fmaf(xs[nn][d], w[d * DIM + o], a0);
            float alpha = 1.f / (1.f + __expf(-skip[t]));
            float hp = h[(size_t)nodes[nn] * DIM + o];
            hcs[nn][o] = a0 * alpha + hp * (1.f - alpha);
        }
    }
    __syncthreads();
    {
        int g = o >> 4, j = o & 15;
        if (nodes[g] >= 0) {
            float s = 0.f;
            for (int d = j; d < DIM; d += 16) s += hcs[g][d];
            #pragma unroll
            for (int m = 1; m < 16; m <<= 1) s += __shfl_xor(s, m);
            float mu = s * (1.f / DIM);
            float v = 0.f;
            for (int d = j; d < DIM; d += 16) { float dv = hcs[g][d] - mu; v = fmaf(dv, dv, v); }
            #pragma unroll
            for (int m = 1; m < 16; m <<= 1) v += __shfl_xor(v, m);
            if (j == 0) { mu_s[g] = mu; rs_s[g] = rsqrtf(v * (1.f / DIM) + 1e-5f); }
        }
    }
    __syncthreads();
    float g_o = ln_g[o], b_o = ln_b[o];
    #pragma unroll
    for (int nn = 0; nn < GN; nn++) {
        if (nodes[nn] >= 0) {
            float hp = h[(size_t)nodes[nn] * DIM + o];
            h[(size_t)nodes[nn] * DIM + o] = (hcs[nn][o] - mu_s[nn]) * rs_s[nn] * g_o + b_o + hp;
        }
    }
}

// ================= host =================

extern "C" void kernel_launch(void* const* d_in, const int* in_sizes, int n_in,
                              void* d_out, int out_size, void* d_ws, size_t ws_size,
                              hipStream_t stream) {
    const float* embed = (const float*)d_in[0];
    const float* Wk    = (const float*)d_in[1];
    const float* Wq    = (const float*)d_in[2];
    const float* Wv    = (const float*)d_in[3];
    const float* Wa    = (const float*)d_in[4];
    const float* ratt  = (const float*)d_in[5];
    const float* rmsg  = (const float*)d_in[6];
    const float* rpri  = (const float*)d_in[7];
    const float* skip  = (const float*)d_in[8];
    const float* ln_g  = (const float*)d_in[9];
    const float* ln_b  = (const float*)d_in[10];
    const int*   src   = (const int*)d_in[11];
    const int*   dst   = (const int*)d_in[12];
    const int*   ntype = (const int*)d_in[13];
    const int*   etype = (const int*)d_in[14];

    float* h = (float*)d_out;

    const size_t ND = (size_t)N_NODES * DIM;
    const int nb = (N_NODES + RB - 1) / RB;
    float* kbuf = (float*)d_ws;
    float* qbuf = kbuf + ND;
    float* vbuf = qbuf + ND;
    int* rs2  = (int*)(vbuf + ND);               // NK+1
    int* deg2 = rs2 + (NK + 1);                  // NK
    int* cur2 = deg2 + NK;                       // NK
    int* epk  = cur2 + NK;                       // E
    int* bsum = epk + NEDGE;                     // 2048
    int* rank = bsum + 2048;                     // N
    int* hist = rank + N_NODES;                  // nb*NTYPE
    int* boff = hist + nb * NTYPE;               // nb*NTYPE
    int* typeoff = boff + nb * NTYPE;            // NTYPE
    int* perm = typeoff + NTYPE;                 // N
    float* rmsgT = (float*)(perm + N_NODES);     // L*H*R*256
    unsigned short* vt = (unsigned short*)(rmsgT + (size_t)NLAYER * NHEAD * NREL * 256);
    size_t need_vt = (size_t)((char*)(vt + (size_t)N_NODES * NREL * DIM) - (char*)d_ws);
    const bool use_vt = (ws_size >= need_vt);
    float* agg = qbuf;                           // alias: q dead once fused block reads its row

    const int EB = (NEDGE + 255) / 256;
    const int nb2 = (NK + 255) / 256;

    // ---- init: rank-within-type, embedding, type permutation ----
    k_hist<<<nb, RB, 0, stream>>>(ntype, hist, N_NODES);
    k_prefix<<<1, 64, 0, stream>>>(hist, boff, nb);
    k_rank<<<nb, RB, 0, stream>>>(ntype, boff, rank, N_NODES);
    k_embed<<<N_NODES, DIM, 0, stream>>>(embed, ntype, rank, h);
    k_typeoff<<<1, 64, 0, stream>>>(hist, boff, nb, typeoff);
    k_perm<<<nb, 256, 0, stream>>>(ntype, rank, typeoff, perm, N_NODES);

    // ---- (dst,etype)-sorted CSR build (graph static across layers) ----
    hipMemsetAsync(deg2, 0, (size_t)NK * sizeof(int), stream);
    hipMemsetAsync(cur2, 0, (size_t)NK * sizeof(int), stream);
    k_deg2<<<EB, 256, 0, stream>>>(dst, etype, deg2);
    k_scan1<<<nb2, 256, 0, stream>>>(deg2, rs2, bsum, NK);
    k_scan2b<<<1, 256, 0, stream>>>(bsum, nb2);
    k_scan3<<<nb2, 256, 0, stream>>>(rs2, bsum, NK);
    k_scatter2<<<EB, 256, 0, stream>>>(src, dst, etype, rs2, cur2, epk);

    // ---- rmsg transpose (all layers) ----
    k_rmsgT<<<NLAYER * NHEAD * NREL, 256, 0, stream>>>(rmsg, rmsgT);

    const int NGB = N_NODES / GN;

    for (int l = 0; l < NLAYER; l++) {
        const float* Wk_l = Wk + (size_t)l * NTYPE * DIM * DIM;
        const float* Wq_l = Wq + (size_t)l * NTYPE * DIM * DIM;
        const float* Wv_l = Wv + (size_t)l * NTYPE * DIM * DIM;
        const float* Wa_l = Wa + (size_t)l * NTYPE * DIM * DIM;
        const float* ratt_l = ratt + (size_t)l * NHEAD * NREL * HDIM * HDIM;
        const float* rmsgT_l = rmsgT + (size_t)l * NHEAD * NREL * HDIM * HDIM;
        const float* rpri_l = rpri + (size_t)l * NHEAD * NREL;
        const float* skip_l = skip + (size_t)l * NTYPE;
        const float* g_l = ln_g + (size_t)l * DIM;
        const float* b_l = ln_b + (size_t)l * DIM;

        k_qkv_g<<<NGB, 128, 0, stream>>>(h, perm, ntype, Wk_l, Wq_l, Wv_l,
                                         kbuf, qbuf, vbuf, N_NODES);
        if (use_vt) {
            k_vt<<<NGB, 128, 0, stream>>>(vbuf, rmsgT_l, vt);
            k_fused4<0><<<N_NODES, 128, 0, stream>>>(kbuf, qbuf, vbuf, vt, rs2, epk,
                                                     ratt_l, rmsgT_l, rpri_l, agg);
        } else {
            k_fused4<1><<<N_NODES, 128, 0, stream>>>(kbuf, qbuf, vbuf, vt, rs2, epk,
                                                     ratt_l, rmsgT_l, rpri_l, agg);
        }
        k_out_g<<<NGB, 128, 0, stream>>>(agg, h, perm, ntype, Wa_l, skip_l, g_l, b_l, N_NODES);
    }
}